// Round 9
// baseline (481.611 us; speedup 1.0000x reference)
//
#include <hip/hip_runtime.h>
#include <math.h>

#define EPSF 1e-5f
#define NNC 46656

typedef __attribute__((ext_vector_type(4))) float  f32x4;
typedef __attribute__((ext_vector_type(8))) short  short8;
typedef __attribute__((ext_vector_type(8))) unsigned short ushort8;
typedef __attribute__((ext_vector_type(4))) unsigned int uint4v;

__device__ __forceinline__ float bf2f(unsigned short u) {
    unsigned int x = ((unsigned int)u) << 16;
    return __builtin_bit_cast(float, x);
}
__device__ __forceinline__ unsigned short f2bf(float f) {
    unsigned int x = __builtin_bit_cast(unsigned int, f);
    unsigned int r = (x + 0x7fffu + ((x >> 16) & 1u)) >> 16;
    return (unsigned short)r;
}

// packed: relu(bf16x2(H) + bf16x2(S)) -> bf16x2 (truncation pack via v_perm)
__device__ __forceinline__ short8 packrelu8(ushort8 H8, ushort8 S8) {
    uint4v H = __builtin_bit_cast(uint4v, H8);
    uint4v S = __builtin_bit_cast(uint4v, S8);
    uint4v O;
#pragma unroll
    for (int d = 0; d < 4; ++d) {
        float hlo = __builtin_bit_cast(float, H[d] << 16);
        float hhi = __builtin_bit_cast(float, H[d] & 0xffff0000u);
        float slo = __builtin_bit_cast(float, S[d] << 16);
        float shi = __builtin_bit_cast(float, S[d] & 0xffff0000u);
        unsigned int rlo = __builtin_bit_cast(unsigned int, fmaxf(hlo + slo, 0.f));
        unsigned int rhi = __builtin_bit_cast(unsigned int, fmaxf(hhi + shi, 0.f));
        O[d] = __builtin_amdgcn_perm(rhi, rlo, 0x07060302u);
    }
    return __builtin_bit_cast(short8, O);
}

// ---- workspace layout (float offsets) ----
#define WS_PP    0u          // P' [36][1024] f32
#define WS_C1    36864u      // [1024] f32
#define WS_SH    37888u      // Sh bf16 [216][1024] -> 110592 f
#define WS_S3    148480u     // S3 bf16 [216][1024] -> 110592 f
#define WS_W2BF  259072u     // W2 bf16 [256][1024] -> 131072 f
#define WS_C2    390144u     // [256] f32
#define WS_W3BF  390400u     // W3 bf16 [784][256] -> 100352 f
#define WS_C3    490752u     // [16] f32
#define WS_XBF   490768u     // X bf16 [64][160] -> 5120 f
#define WS_SX2   495888u     // [64] f32
#define WS_E1T   495952u     // e1n^T [256 o][64 b] f32 -> 16384 f
#define WS_E2T   512336u     // e2n^T [1024 j][64 b] f32 -> 65536 f
#define WS_H2G   577872u     // h2 bf16 [729][32 kb][64 m][8] -> 5971968 f
#define WS_NEED_BYTES ((size_t)(577872u + 5971968u) * 4)

#define OBS_SIZE (64*NNC)
#define DIST_OFF OBS_SIZE
#define LOSS_OFF (OBS_SIZE + 64*36)

#define LDS_FUSED 75008
#define LDS_K3B   42240

// ============================ K1: coalesced prep + conv/BN ============================
// blocks: [0,64) P'+c1 | [64,320) W2 | [320,336) W3 | 336 X | [337,401) conv+BN

__global__ void dvae_k1(const float* __restrict__ x,
                        const float* __restrict__ conv_w, const float* __restrict__ conv_b,
                        const float* __restrict__ ebn2_g, const float* __restrict__ ebn2_b,
                        const float* __restrict__ embeds, const float* __restrict__ dfc1_w,
                        const float* __restrict__ dfc1_b,
                        const float* __restrict__ dbn1_g, const float* __restrict__ dbn1_b,
                        const float* __restrict__ dbn1_rm, const float* __restrict__ dbn1_rv,
                        const float* __restrict__ dfc2_w, const float* __restrict__ dfc2_b,
                        const float* __restrict__ dbn2_g, const float* __restrict__ dbn2_b,
                        const float* __restrict__ dbn2_rm, const float* __restrict__ dbn2_rv,
                        const float* __restrict__ dct1_w, const float* __restrict__ dct1_b,
                        const float* __restrict__ dbn3_g, const float* __restrict__ dbn3_b,
                        const float* __restrict__ dbn3_rm, const float* __restrict__ dbn3_rv,
                        float* __restrict__ ws) {
    __shared__ float sbuf[12544];
    int bx = blockIdx.x, tid = threadIdx.x;
    if (bx < 64) {                       // ---- P' [36][1024] + c1 (64 blocks, 16 j each) ----
        float* wtile = sbuf;             // [16][193]
        float* semb  = sbuf + 3088;      // [1152]
        int j0 = bx * 16;
        for (int e = tid; e < 16 * 192; e += 256)
            wtile[(e / 192) * 193 + (e % 192)] = dfc1_w[j0 * 192 + e];
        for (int e = tid; e < 1152; e += 256) semb[e] = embeds[e];
        __syncthreads();
        int jL = tid & 15, vk0 = tid >> 4;
        int j = j0 + jL;
        float s1 = dbn1_g[j] * rsqrtf(dbn1_rv[j] + EPSF);
        for (int vk = vk0; vk < 36; vk += 16) {
            int v = vk / 6;
            const float* wrow = &wtile[jL * 193 + v * 32];
            const float* ep = &semb[vk * 32];
            float dot = 0.f;
#pragma unroll
            for (int d = 0; d < 32; ++d) dot += wrow[d] * ep[d];
            ws[WS_PP + vk * 1024 + j] = s1 * dot;
        }
        if (tid < 16) {
            int jj = j0 + tid;
            float s = dbn1_g[jj] * rsqrtf(dbn1_rv[jj] + EPSF);
            ws[WS_C1 + jj] = s * dfc1_b[jj] + dbn1_b[jj] - dbn1_rm[jj] * s;
        }
    } else if (bx < 320) {               // ---- W2 bf16 + c2 ----
        int t = (bx - 64) * 256 + tid;
        int i = t >> 8, kq = (t & 255) * 4;
        float s2 = dbn2_g[i] * rsqrtf(dbn2_rv[i] + EPSF);
        float4 w = *(const float4*)(dfc2_w + i * 1024 + kq);
        unsigned short* dst = (unsigned short*)(ws + WS_W2BF) + i * 1024 + kq;
        dst[0] = f2bf(s2 * w.x); dst[1] = f2bf(s2 * w.y);
        dst[2] = f2bf(s2 * w.z); dst[3] = f2bf(s2 * w.w);
        if (kq == 0) ws[WS_C2 + i] = s2 * dfc2_b[i] + dbn2_b[i] - dbn2_rm[i] * s2;
    } else if (bx < 336) {               // ---- W3 bf16 + c3 (LDS transpose) ----
        int blk = bx - 320;
        for (int e = tid; e < 12544; e += 256) sbuf[e] = dct1_w[blk * 12544 + e];
        __syncthreads();
        unsigned short* W3 = (unsigned short*)(ws + WS_W3BF);
        for (int e = tid; e < 1568; e += 256) {
            int up = e >> 1, k8 = (e & 1) * 8;
            int o = up & 15, hw = up >> 4;
            float s3 = dbn3_g[o] * rsqrtf(dbn3_rv[o] + EPSF);
            ushort8 ov;
#pragma unroll
            for (int t2 = 0; t2 < 8; ++t2)
                ov[t2] = f2bf(s3 * sbuf[(k8 + t2) * 784 + o * 49 + hw]);
            *(ushort8*)(W3 + up * 256 + blk * 16 + k8) = ov;
        }
        if (blk == 0 && tid < 16) {
            float s = dbn3_g[tid] * rsqrtf(dbn3_rv[tid] + EPSF);
            ws[WS_C3 + tid] = s * dct1_b[tid] + dbn3_b[tid] - dbn3_rm[tid] * s;
        }
    } else if (bx == 336) {              // ---- X bf16 + sum(x^2) ----
        unsigned short* Xb = (unsigned short*)(ws + WS_XBF);
        if (tid < 64) {
            const float* xp = x + tid * 147;
            float s = 0.f;
            for (int qq = 0; qq < 147; ++qq) { float v = xp[qq]; s += v * v; }
            ws[WS_SX2 + tid] = s;
        }
        for (int e = tid; e < 64 * 160; e += 256) {
            int b = e / 160, col = e % 160;
            float v = 0.f;
            if (col < 147) { int hw = col / 3, c = col % 3; v = x[b * 147 + c * 49 + hw]; }
            Xb[e] = f2bf(v);
        }
    } else {                             // ---- conv + BN-train (x staged in LDS) ----
        int blk = bx - 337;
        for (int e = tid; e < 9408; e += 256) sbuf[e] = x[e];
        __syncthreads();
        int b = tid & 63;
        int oL = __builtin_amdgcn_readfirstlane(tid >> 6);
        int o = blk * 4 + oL;
        const float* wp = conv_w + o * 147;
        float acc = conv_b[o];
        for (int qq = 0; qq < 147; ++qq) acc += sbuf[b * 147 + qq] * wp[qq];
        float m = acc;
#pragma unroll
        for (int s = 1; s < 64; s <<= 1) m += __shfl_xor(m, s);
        m *= (1.f / 64.f);
        float d = acc - m;
        float var = d * d;
#pragma unroll
        for (int s = 1; s < 64; s <<= 1) var += __shfl_xor(var, s);
        var *= (1.f / 64.f);
        float y = ebn2_g[o] * d * rsqrtf(var + EPSF) + ebn2_b[o];
        ws[WS_E1T + o * 64 + b] = fmaxf(y, 0.f);
    }
}

// ============================ K2: Sh/S3 tables + fc1/BN ============================

__global__ void dvae_k2(const float* __restrict__ fc1_w, const float* __restrict__ fc1_b,
                        const float* __restrict__ ebn1_g, const float* __restrict__ ebn1_b,
                        float* __restrict__ ws) {
    int bx = blockIdx.x, tid = threadIdx.x;
    const float* Pp = ws + WS_PP;
    if (bx < 108) {
        int t = bx * 256 + tid;
        int gh = t >> 7, kg = (t & 127) * 8;
        int d0 = gh / 36, d1 = (gh / 6) % 6, d2 = gh % 6;
        const float* r0 = Pp + d0 * 1024 + kg;
        const float* r1 = Pp + (6 + d1) * 1024 + kg;
        const float* r2 = Pp + (12 + d2) * 1024 + kg;
        const float* cc = ws + WS_C1 + kg;
        ushort8 o;
#pragma unroll
        for (int e = 0; e < 8; ++e) o[e] = f2bf(cc[e] + r0[e] + r1[e] + r2[e]);
        *(ushort8*)((unsigned short*)(ws + WS_SH) + gh * 1024 + kg) = o;
    } else if (bx < 216) {
        int t = (bx - 108) * 256 + tid;
        int gl = t >> 7, kg = (t & 127) * 8;
        int d3 = gl / 36, d4 = (gl / 6) % 6, d5 = gl % 6;
        const float* r3 = Pp + (18 + d3) * 1024 + kg;
        const float* r4 = Pp + (24 + d4) * 1024 + kg;
        const float* r5 = Pp + (30 + d5) * 1024 + kg;
        ushort8 o;
#pragma unroll
        for (int e = 0; e < 8; ++e) o[e] = f2bf(r3[e] + r4[e] + r5[e]);
        *(ushort8*)((unsigned short*)(ws + WS_S3) + gl * 1024 + kg) = o;
    } else {
        int blk = bx - 216;
        int b = tid & 63;
        int jL = __builtin_amdgcn_readfirstlane(tid >> 6);
        int j = blk * 4 + jL;
        const float* e1 = ws + WS_E1T;
        const float* wp = fc1_w + j * 256;
        float acc = fc1_b[j];
        for (int o = 0; o < 256; ++o) acc += e1[o * 64 + b] * wp[o];
        float m = acc;
#pragma unroll
        for (int s = 1; s < 64; s <<= 1) m += __shfl_xor(m, s);
        m *= (1.f / 64.f);
        float d = acc - m;
        float var = d * d;
#pragma unroll
        for (int s = 1; s < 64; s <<= 1) var += __shfl_xor(var, s);
        var *= (1.f / 64.f);
        float y = ebn1_g[j] * d * rsqrtf(var + EPSF) + ebn1_b[j];
        ws[WS_E2T + j * 64 + b] = fmaxf(y, 0.f);
    }
}

// ============================ K3a: GEMM2 -> h2 in global (zero LDS) ============================

__launch_bounds__(256, 3)
__global__ void dvae_k3a(const unsigned short* __restrict__ Sh,
                         const unsigned short* __restrict__ S3g,
                         const unsigned short* __restrict__ W2,
                         const float* __restrict__ c2g,
                         unsigned short* __restrict__ h2g) {
    int tid = threadIdx.x;
    int wv = tid >> 6, lane = tid & 63, l15 = lane & 15, q = lane >> 4;
    int blk = blockIdx.x;
    int nbase = blk * 64;

    f32x4 acc[4][4];
#pragma unroll
    for (int a = 0; a < 4; ++a)
#pragma unroll
        for (int b = 0; b < 4; ++b) acc[a][b] = (f32x4){0.f, 0.f, 0.f, 0.f};

    const unsigned short* pSh[4];
    const unsigned short* pS3[4];
#pragma unroll
    for (int mt = 0; mt < 4; ++mt) {
        int nm = nbase + mt * 16 + l15;
        int gh = nm / 216;
        int r216 = nm - gh * 216;
        pSh[mt] = Sh + gh * 1024 + q * 8;
        pS3[mt] = S3g + r216 * 1024 + q * 8;
    }
    const unsigned short* bbase = W2 + (wv * 64 + l15) * 1024 + q * 8;

    ushort8 sa[4], sb[4];
    short8 bpre[4];
#pragma unroll
    for (int mt = 0; mt < 4; ++mt) { sa[mt] = *(const ushort8*)(pSh[mt]); sb[mt] = *(const ushort8*)(pS3[mt]); }
#pragma unroll
    for (int j = 0; j < 4; ++j) bpre[j] = *(const short8*)(bbase + j * 16384);

#pragma unroll 2
    for (int s = 0; s < 32; ++s) {
        short8 af[4];
#pragma unroll
        for (int mt = 0; mt < 4; ++mt) af[mt] = packrelu8(sa[mt], sb[mt]);
        short8 bcur[4];
#pragma unroll
        for (int j = 0; j < 4; ++j) bcur[j] = bpre[j];
        if (s < 31) {
            int off = (s + 1) * 32;
#pragma unroll
            for (int mt = 0; mt < 4; ++mt) {
                sa[mt] = *(const ushort8*)(pSh[mt] + off);
                sb[mt] = *(const ushort8*)(pS3[mt] + off);
            }
#pragma unroll
            for (int j = 0; j < 4; ++j) bpre[j] = *(const short8*)(bbase + j * 16384 + off);
        }
#pragma unroll
        for (int mt = 0; mt < 4; ++mt)
#pragma unroll
            for (int j = 0; j < 4; ++j)
                acc[mt][j] = __builtin_amdgcn_mfma_f32_16x16x32_bf16(af[mt], bcur[j], acc[mt][j], 0, 0, 0);
    }
    // epilogue -> h2g bf16 [blk][kb=i>>3][m][i&7]
    unsigned short* hb = h2g + (size_t)blk * 16384;
#pragma unroll
    for (int j = 0; j < 4; ++j) {
        int i = wv * 64 + j * 16 + l15;
        int kb = i >> 3, io = i & 7;
        float cc = c2g[i];
#pragma unroll
        for (int mt = 0; mt < 4; ++mt)
#pragma unroll
            for (int r = 0; r < 4; ++r) {
                int m = mt * 16 + q * 4 + r;
                hb[(kb * 64 + m) * 8 + io] = f2bf(fmaxf(acc[mt][j][r] + cc, 0.f));
            }
    }
}

// ============================ K3b: GEMM3 + proj + obs (+ logits block 0) ============================

__launch_bounds__(256, 3)
__global__ void dvae_k3b(const unsigned short* __restrict__ h2g,
                         const unsigned short* __restrict__ W3,
                         const float* __restrict__ c3g,
                         const float* __restrict__ d2wg,
                         const float* __restrict__ d2bg,
                         const unsigned short* __restrict__ Xg,
                         const float* __restrict__ sx2g,
                         const float* __restrict__ e2T,
                         const float* __restrict__ fc2_w,
                         const float* __restrict__ fc2_b,
                         float* __restrict__ out) {
    extern __shared__ char sm[];
    int tid = threadIdx.x;

    if (blockIdx.x == 0) {
        // ---- logits via 64-wide LDS chunks + softmax + entropy ----
        float* wch = (float*)sm;              // [36][64]
        float* ech = (float*)(sm + 9216);     // [64][64]
        float* LG  = (float*)(sm + 25600);    // [64][36]
        int b = tid & 63;
        int wvU = __builtin_amdgcn_readfirstlane(tid >> 6);
        float accv[9];
#pragma unroll
        for (int it = 0; it < 9; ++it) accv[it] = 0.f;
        for (int ch = 0; ch < 16; ++ch) {
            __syncthreads();
            for (int e = tid; e < 36 * 64; e += 256)
                wch[e] = fc2_w[(e >> 6) * 1024 + ch * 64 + (e & 63)];
            for (int e = tid; e < 64 * 64; e += 256)
                ech[e] = e2T[(ch * 64 + (e >> 6)) * 64 + (e & 63)];
            __syncthreads();
            for (int jl = 0; jl < 64; ++jl) {
                float ev = ech[jl * 64 + b];
#pragma unroll
                for (int it = 0; it < 9; ++it)
                    accv[it] += ev * wch[(wvU + it * 4) * 64 + jl];
            }
        }
#pragma unroll
        for (int it = 0; it < 9; ++it) {
            int o = wvU + it * 4;
            LG[b * 36 + o] = accv[it] + fc2_b[o];
        }
        __syncthreads();
        if (tid < 64) {
            float loss = 0.f;
#pragma unroll
            for (int v = 0; v < 6; ++v) {
                float mx = -1e30f;
#pragma unroll
                for (int k = 0; k < 6; ++k) mx = fmaxf(mx, LG[tid * 36 + v * 6 + k]);
                float s = 0.f, ex[6];
#pragma unroll
                for (int k = 0; k < 6; ++k) { ex[k] = expf(LG[tid * 36 + v * 6 + k] - mx); s += ex[k]; }
                float inv = 1.f / s;
#pragma unroll
                for (int k = 0; k < 6; ++k) {
                    float dd = ex[k] * inv;
                    out[DIST_OFF + tid * 36 + v * 6 + k] = dd;
                    loss += dd * logf(dd + 1e-10f);
                }
            }
            out[LOSS_OFF + tid] = 0.1f * loss;
        }
        return;
    }

    int wv = tid >> 6, lane = tid & 63, l15 = lane & 15, q = lane >> 4;
    int blk = blockIdx.x - 1;
    int nbase = blk * 64;
    float* sE2p = (float*)(sm + 0);
    float* sE2f = (float*)(sm + 1024);
    unsigned short* emL = (unsigned short*)(sm + 1280);   // [64][160]
    float* h3w = (float*)(sm + 21760 + wv * 5120);        // per-wave [64][20] f32
    const unsigned short* h2b = h2g + (size_t)blk * 16384;

    float c3v = c3g[l15];
    float db0 = d2bg[0], db1 = d2bg[1], db2 = d2bg[2];
    float dw0[16], dw1[16], dw2[16];
#pragma unroll
    for (int o = 0; o < 16; ++o) {
        dw0[o] = d2wg[o * 3 + 0]; dw1[o] = d2wg[o * 3 + 1]; dw2[o] = d2wg[o * 3 + 2];
    }
    float sE2a = 0.f;
    for (int c = wv; c < 13; c += 4) {
        int hw0 = c * 4;
        f32x4 a2[4][4];
#pragma unroll
        for (int a = 0; a < 4; ++a)
#pragma unroll
            for (int b = 0; b < 4; ++b) a2[a][b] = (f32x4){0.f, 0.f, 0.f, 0.f};
        const unsigned short* b3[4];
#pragma unroll
        for (int j = 0; j < 4; ++j) {
            int hw = hw0 + j; if (hw > 48) hw = 48;
            b3[j] = W3 + (hw * 16 + l15) * 256 + q * 8;
        }
        short8 bpre2[4], apre[4];
#pragma unroll
        for (int j = 0; j < 4; ++j) bpre2[j] = *(const short8*)(b3[j]);
#pragma unroll
        for (int mt = 0; mt < 4; ++mt)
            apre[mt] = *(const short8*)(h2b + (q * 64 + mt * 16 + l15) * 8);
#pragma unroll
        for (int s = 0; s < 8; ++s) {
            short8 bcur[4], af[4];
#pragma unroll
            for (int j = 0; j < 4; ++j) bcur[j] = bpre2[j];
#pragma unroll
            for (int mt = 0; mt < 4; ++mt) af[mt] = apre[mt];
            if (s < 7) {
#pragma unroll
                for (int j = 0; j < 4; ++j) bpre2[j] = *(const short8*)(b3[j] + (s + 1) * 32);
#pragma unroll
                for (int mt = 0; mt < 4; ++mt)
                    apre[mt] = *(const short8*)(h2b + (((s + 1) * 4 + q) * 64 + mt * 16 + l15) * 8);
            }
#pragma unroll
            for (int mt = 0; mt < 4; ++mt)
#pragma unroll
                for (int j = 0; j < 4; ++j)
                    a2[mt][j] = __builtin_amdgcn_mfma_f32_16x16x32_bf16(af[mt], bcur[j], a2[mt][j], 0, 0, 0);
        }
#pragma unroll
        for (int j = 0; j < 4; ++j) {
            int hw = hw0 + j;
            if (hw <= 48) {
#pragma unroll
                for (int mt = 0; mt < 4; ++mt)
#pragma unroll
                    for (int r = 0; r < 4; ++r)
                        h3w[(mt * 16 + q * 4 + r) * 20 + l15] = fmaxf(a2[mt][j][r] + c3v, 0.f);
                float hvv[16];
#pragma unroll
                for (int g = 0; g < 4; ++g) {
                    f32x4 tv = *(const f32x4*)(h3w + lane * 20 + g * 4);
                    hvv[g * 4 + 0] = tv[0]; hvv[g * 4 + 1] = tv[1];
                    hvv[g * 4 + 2] = tv[2]; hvv[g * 4 + 3] = tv[3];
                }
                float e0 = db0, e1 = db1, e2 = db2;
#pragma unroll
                for (int o = 0; o < 16; ++o) {
                    e0 += hvv[o] * dw0[o]; e1 += hvv[o] * dw1[o]; e2 += hvv[o] * dw2[o];
                }
                unsigned short u0 = f2bf(e0), u1 = f2bf(e1), u2 = f2bf(e2);
                float f0 = bf2f(u0), f1 = bf2f(u1), f2v = bf2f(u2);
                sE2a += f0 * f0 + f1 * f1 + f2v * f2v;
                emL[lane * 160 + hw * 3 + 0] = u0;
                emL[lane * 160 + hw * 3 + 1] = u1;
                emL[lane * 160 + hw * 3 + 2] = u2;
            }
        }
    }
    sE2p[wv * 64 + lane] = sE2a;
    for (int e = tid; e < 64 * 13; e += 256) emL[(e / 13) * 160 + 147 + (e % 13)] = 0;
    __syncthreads();
    if (tid < 64) sE2f[tid] = sE2p[tid] + sE2p[64 + tid] + sE2p[128 + tid] + sE2p[192 + tid];
    __syncthreads();

    f32x4 aO[4];
#pragma unroll
    for (int j = 0; j < 4; ++j) aO[j] = (f32x4){0.f, 0.f, 0.f, 0.f};
    const unsigned short* xrow = Xg + (wv * 16 + l15) * 160 + q * 8;
#pragma unroll
    for (int s = 0; s < 5; ++s) {
        short8 af = *(const short8*)(xrow + s * 32);
#pragma unroll
        for (int j = 0; j < 4; ++j) {
            short8 bfv = *(const short8*)(emL + (j * 16 + l15) * 160 + s * 32 + q * 8);
            aO[j] = __builtin_amdgcn_mfma_f32_16x16x32_bf16(af, bfv, aO[j], 0, 0, 0);
        }
    }
    int b0 = wv * 16 + q * 4;
    float sxv[4];
#pragma unroll
    for (int r = 0; r < 4; ++r) sxv[r] = sx2g[b0 + r];
#pragma unroll
    for (int j = 0; j < 4; ++j) {
        int n = nbase + j * 16 + l15;
        float he = 0.5f * sE2f[j * 16 + l15];
#pragma unroll
        for (int r = 0; r < 4; ++r)
            out[(size_t)(b0 + r) * NNC + n] = aO[j][r] - he - 0.5f * sxv[r];
    }
}

// ============================ K3f: fused decoder (R8 verbatim, ws fallback) ============================

__launch_bounds__(256, 2)
__global__ void dvae_k3f(const unsigned short* __restrict__ Sh,
                         const unsigned short* __restrict__ S3g,
                         const unsigned short* __restrict__ W2,
                         const float* __restrict__ c2g,
                         const unsigned short* __restrict__ W3,
                         const float* __restrict__ c3g,
                         const float* __restrict__ d2wg,
                         const float* __restrict__ d2bg,
                         const unsigned short* __restrict__ Xg,
                         const float* __restrict__ sx2g,
                         const float* __restrict__ e2T,
                         const float* __restrict__ fc2_w,
                         const float* __restrict__ fc2_b,
                         float* __restrict__ out) {
    extern __shared__ char sm[];
    int tid = threadIdx.x;

    if (blockIdx.x == 0) {
        float* wch = (float*)sm;
        float* ech = (float*)(sm + 18432);
        float* LG  = (float*)(sm + 51200);
        int b = tid & 63;
        int wvU = __builtin_amdgcn_readfirstlane(tid >> 6);
        float accv[9];
#pragma unroll
        for (int it = 0; it < 9; ++it) accv[it] = 0.f;
        for (int ch = 0; ch < 8; ++ch) {
            __syncthreads();
            for (int e = tid; e < 36 * 128; e += 256)
                wch[e] = fc2_w[(e >> 7) * 1024 + ch * 128 + (e & 127)];
            for (int e = tid; e < 128 * 64; e += 256)
                ech[e] = e2T[(ch * 128 + (e >> 6)) * 64 + (e & 63)];
            __syncthreads();
            for (int jl = 0; jl < 128; ++jl) {
                float ev = ech[jl * 64 + b];
#pragma unroll
                for (int it = 0; it < 9; ++it)
                    accv[it] += ev * wch[(wvU + it * 4) * 128 + jl];
            }
        }
#pragma unroll
        for (int it = 0; it < 9; ++it) {
            int o = wvU + it * 4;
            LG[b * 36 + o] = accv[it] + fc2_b[o];
        }
        __syncthreads();
        if (tid < 64) {
            float loss = 0.f;
#pragma unroll
            for (int v = 0; v < 6; ++v) {
                float mx = -1e30f;
#pragma unroll
                for (int k = 0; k < 6; ++k) mx = fmaxf(mx, LG[tid * 36 + v * 6 + k]);
                float s = 0.f, ex[6];
#pragma unroll
                for (int k = 0; k < 6; ++k) { ex[k] = expf(LG[tid * 36 + v * 6 + k] - mx); s += ex[k]; }
                float inv = 1.f / s;
#pragma unroll
                for (int k = 0; k < 6; ++k) {
                    float dd = ex[k] * inv;
                    out[DIST_OFF + tid * 36 + v * 6 + k] = dd;
                    loss += dd * logf(dd + 1e-10f);
                }
            }
            out[LOSS_OFF + tid] = 0.1f * loss;
        }
        return;
    }

    int wv = tid >> 6, lane = tid & 63, l15 = lane & 15, q = lane >> 4;
    int nbase = (blockIdx.x - 1) * 64;
    float* sE2p = (float*)(sm + 0);
    float* sE2f = (float*)(sm + 1024);
    unsigned short* emL = (unsigned short*)(sm + 1280);
    float* h3w = (float*)(sm + 21760 + wv * 5120);
    unsigned short* h2L = (unsigned short*)(sm + 42240);

    f32x4 acc[4][4];
#pragma unroll
    for (int a = 0; a < 4; ++a)
#pragma unroll
        for (int b = 0; b < 4; ++b) acc[a][b] = (f32x4){0.f, 0.f, 0.f, 0.f};

    const unsigned short* pSh[4];
    const unsigned short* pS3[4];
#pragma unroll
    for (int mt = 0; mt < 4; ++mt) {
        int nm = nbase + mt * 16 + l15;
        int gh = nm / 216;
        int r216 = nm - gh * 216;
        pSh[mt] = Sh + gh * 1024 + q * 8;
        pS3[mt] = S3g + r216 * 1024 + q * 8;
    }
    const unsigned short* bbase = W2 + (wv * 64 + l15) * 1024 + q * 8;

    ushort8 sa[4], sb[4];
    short8 bpre[4];
#pragma unroll
    for (int mt = 0; mt < 4; ++mt) { sa[mt] = *(const ushort8*)(pSh[mt]); sb[mt] = *(const ushort8*)(pS3[mt]); }
#pragma unroll
    for (int j = 0; j < 4; ++j) bpre[j] = *(const short8*)(bbase + j * 16384);

#pragma unroll 2
    for (int s = 0; s < 32; ++s) {
        short8 af[4];
#pragma unroll
        for (int mt = 0; mt < 4; ++mt) af[mt] = packrelu8(sa[mt], sb[mt]);
        short8 bcur[4];
#pragma unroll
        for (int j = 0; j < 4; ++j) bcur[j] = bpre[j];
        if (s < 31) {
            int off = (s + 1) * 32;
#pragma unroll
            for (int mt = 0; mt < 4; ++mt) {
                sa[mt] = *(const ushort8*)(pSh[mt] + off);
                sb[mt] = *(const ushort8*)(pS3[mt] + off);
            }
#pragma unroll
            for (int j = 0; j < 4; ++j) bpre[j] = *(const short8*)(bbase + j * 16384 + off);
        }
#pragma unroll
        for (int mt = 0; mt < 4; ++mt)
#pragma unroll
            for (int j = 0; j < 4; ++j)
                acc[mt][j] = __builtin_amdgcn_mfma_f32_16x16x32_bf16(af[mt], bcur[j], acc[mt][j], 0, 0, 0);
    }
#pragma unroll
    for (int j = 0; j < 4; ++j) {
        int i = wv * 64 + j * 16 + l15;
        float cc = c2g[i];
#pragma unroll
        for (int mt = 0; mt < 4; ++mt)
#pragma unroll
            for (int r = 0; r < 4; ++r) {
                int m = mt * 16 + q * 4 + r;
                h2L[((i >> 3) * 64 + m) * 8 + (i & 7)] = f2bf(fmaxf(acc[mt][j][r] + cc, 0.f));
            }
    }
    __syncthreads();

    float c3v = c3g[l15];
    float db0 = d2bg[0], db1 = d2bg[1], db2 = d2bg[2];
    float dw0[16], dw1[16], dw2[16];
#pragma unroll
    for (int o = 0; o < 16; ++o) {
        dw0[o] = d2wg[o * 3 + 0]; dw1[o] = d2wg[o * 3 + 1]; dw2[o] = d2wg[o * 3 + 2];
    }
    float sE2a = 0.f;
    for (int c = wv; c < 13; c += 4) {
        int hw0 = c * 4;
        f32x4 a2[4][4];
#pragma unroll
        for (int a = 0; a < 4; ++a)
#pragma unroll
            for (int b = 0; b < 4; ++b) a2[a][b] = (f32x4){0.f, 0.f, 0.f, 0.f};
        const unsigned short* b3[4];
#pragma unroll
        for (int j = 0; j < 4; ++j) {
            int hw = hw0 + j; if (hw > 48) hw = 48;
            b3[j] = W3 + (hw * 16 + l15) * 256 + q * 8;
        }
        short8 bpre2[4];
#pragma unroll
        for (int j = 0; j < 4; ++j) bpre2[j] = *(const short8*)(b3[j]);
#pragma unroll
        for (int s = 0; s < 8; ++s) {
            short8 bcur[4];
#pragma unroll
            for (int j = 0; j < 4; ++j) bcur[j] = bpre2[j];
            if (s < 7) {
#pragma unroll
                for (int j = 0; j < 4; ++j) bpre2[j] = *(const short8*)(b3[j] + (s + 1) * 32);
            }
            short8 af[4];
#pragma unroll
            for (int mt = 0; mt < 4; ++mt)
                af[mt] = *(const short8*)(h2L + ((s * 4 + q) * 64 + mt * 16 + l15) * 8);
#pragma unroll
            for (int mt = 0; mt < 4; ++mt)
#pragma unroll
                for (int j = 0; j < 4; ++j)
                    a2[mt][j] = __builtin_amdgcn_mfma_f32_16x16x32_bf16(af[mt], bcur[j], a2[mt][j], 0, 0, 0);
        }
#pragma unroll
        for (int j = 0; j < 4; ++j) {
            int hw = hw0 + j;
            if (hw <= 48) {
#pragma unroll
                for (int mt = 0; mt < 4; ++mt)
#pragma unroll
                    for (int r = 0; r < 4; ++r)
                        h3w[(mt * 16 + q * 4 + r) * 20 + l15] = fmaxf(a2[mt][j][r] + c3v, 0.f);
                float hvv[16];
#pragma unroll
                for (int g = 0; g < 4; ++g) {
                    f32x4 tv = *(const f32x4*)(h3w + lane * 20 + g * 4);
                    hvv[g * 4 + 0] = tv[0]; hvv[g * 4 + 1] = tv[1];
                    hvv[g * 4 + 2] = tv[2]; hvv[g * 4 + 3] = tv[3];
                }
                float e0 = db0, e1 = db1, e2 = db2;
#pragma unroll
                for (int o = 0; o < 16; ++o) {
                    e0 += hvv[o] * dw0[o]; e1 += hvv[o] * dw1[o]; e2 += hvv[o] * dw2[o];
                }
                unsigned short u0 = f2bf(e0), u1 = f2bf(e1), u2 = f2bf(e2);
                float f0 = bf2f(u0), f1 = bf2f(u1), f2v = bf2f(u2);
                sE2a += f0 * f0 + f1 * f1 + f2v * f2v;
                emL[lane * 160 + hw * 3 + 0] = u0;
                emL[lane * 160 + hw * 3 + 1] = u1;
                emL[lane * 160 + hw * 3 + 2] = u2;
            }
        }
    }
    sE2p[wv * 64 + lane] = sE2a;
    for (int e = tid; e < 64 * 13; e += 256) emL[(e / 13) * 160 + 147 + (e % 13)] = 0;
    __syncthreads();
    if (tid < 64) sE2f[tid] = sE2p[tid] + sE2p[64 + tid] + sE2p[128 + tid] + sE2p[192 + tid];
    __syncthreads();

    f32x4 aO[4];
#pragma unroll
    for (int j = 0; j < 4; ++j) aO[j] = (f32x4){0.f, 0.f, 0.f, 0.f};
    const unsigned short* xrow = Xg + (wv * 16 + l15) * 160 + q * 8;
#pragma unroll
    for (int s = 0; s < 5; ++s) {
        short8 af = *(const short8*)(xrow + s * 32);
#pragma unroll
        for (int j = 0; j < 4; ++j) {
            short8 bfv = *(const short8*)(emL + (j * 16 + l15) * 160 + s * 32 + q * 8);
            aO[j] = __builtin_amdgcn_mfma_f32_16x16x32_bf16(af, bfv, aO[j], 0, 0, 0);
        }
    }
    int b0 = wv * 16 + q * 4;
    float sxv[4];
#pragma unroll
    for (int r = 0; r < 4; ++r) sxv[r] = sx2g[b0 + r];
#pragma unroll
    for (int j = 0; j < 4; ++j) {
        int n = nbase + j * 16 + l15;
        float he = 0.5f * sE2f[j * 16 + l15];
#pragma unroll
        for (int r = 0; r < 4; ++r)
            out[(size_t)(b0 + r) * NNC + n] = aO[j][r] - he - 0.5f * sxv[r];
    }
}

// ============================ launcher ============================

extern "C" void kernel_launch(void* const* d_in, const int* in_sizes, int n_in,
                              void* d_out, int out_size, void* d_ws, size_t ws_size,
                              hipStream_t stream) {
    const float* x       = (const float*)d_in[0];
    const float* conv_w  = (const float*)d_in[1];
    const float* conv_b  = (const float*)d_in[2];
    const float* ebn2_g  = (const float*)d_in[3];
    const float* ebn2_b  = (const float*)d_in[4];
    const float* fc1_w   = (const float*)d_in[5];
    const float* fc1_b   = (const float*)d_in[6];
    const float* ebn1_g  = (const float*)d_in[7];
    const float* ebn1_b  = (const float*)d_in[8];
    const float* fc2_w   = (const float*)d_in[9];
    const float* fc2_b   = (const float*)d_in[10];
    const float* embeds  = (const float*)d_in[11];
    const float* dfc1_w  = (const float*)d_in[12];
    const float* dfc1_b  = (const float*)d_in[13];
    const float* dbn1_g  = (const float*)d_in[14];
    const float* dbn1_b  = (const float*)d_in[15];
    const float* dbn1_rm = (const float*)d_in[16];
    const float* dbn1_rv = (const float*)d_in[17];
    const float* dfc2_w  = (const float*)d_in[18];
    const float* dfc2_b  = (const float*)d_in[19];
    const float* dbn2_g  = (const float*)d_in[20];
    const float* dbn2_b  = (const float*)d_in[21];
    const float* dbn2_rm = (const float*)d_in[22];
    const float* dbn2_rv = (const float*)d_in[23];
    const float* dct1_w  = (const float*)d_in[24];
    const float* dct1_b  = (const float*)d_in[25];
    const float* dbn3_g  = (const float*)d_in[26];
    const float* dbn3_b  = (const float*)d_in[27];
    const float* dbn3_rm = (const float*)d_in[28];
    const float* dbn3_rv = (const float*)d_in[29];
    const float* dct2_w  = (const float*)d_in[30];
    const float* dct2_b  = (const float*)d_in[31];

    float* ws  = (float*)d_ws;
    float* out = (float*)d_out;

    dvae_k1<<<401, 256, 0, stream>>>(x, conv_w, conv_b, ebn2_g, ebn2_b,
                                     embeds, dfc1_w, dfc1_b, dbn1_g, dbn1_b, dbn1_rm, dbn1_rv,
                                     dfc2_w, dfc2_b, dbn2_g, dbn2_b, dbn2_rm, dbn2_rv,
                                     dct1_w, dct1_b, dbn3_g, dbn3_b, dbn3_rm, dbn3_rv, ws);
    dvae_k2<<<472, 256, 0, stream>>>(fc1_w, fc1_b, ebn1_g, ebn1_b, ws);

    if (ws_size >= WS_NEED_BYTES) {
        unsigned short* h2g = (unsigned short*)(ws + WS_H2G);
        dvae_k3a<<<729, 256, 0, stream>>>(
            (const unsigned short*)(ws + WS_SH), (const unsigned short*)(ws + WS_S3),
            (const unsigned short*)(ws + WS_W2BF), ws + WS_C2, h2g);
        dvae_k3b<<<730, 256, LDS_K3B, stream>>>(
            h2g, (const unsigned short*)(ws + WS_W3BF), ws + WS_C3,
            dct2_w, dct2_b,
            (const unsigned short*)(ws + WS_XBF), ws + WS_SX2,
            ws + WS_E2T, fc2_w, fc2_b, out);
    } else {
        hipFuncSetAttribute(reinterpret_cast<const void*>(dvae_k3f),
                            hipFuncAttributeMaxDynamicSharedMemorySize, LDS_FUSED);
        dvae_k3f<<<730, 256, LDS_FUSED, stream>>>(
            (const unsigned short*)(ws + WS_SH), (const unsigned short*)(ws + WS_S3),
            (const unsigned short*)(ws + WS_W2BF), ws + WS_C2,
            (const unsigned short*)(ws + WS_W3BF), ws + WS_C3,
            dct2_w, dct2_b,
            (const unsigned short*)(ws + WS_XBF), ws + WS_SX2,
            ws + WS_E2T, fc2_w, fc2_b, out);
    }
}

// Round 10
// 375.102 us; speedup vs baseline: 1.2839x; 1.2839x over previous
//
#include <hip/hip_runtime.h>
#include <math.h>

#define EPSF 1e-5f
#define NNC 46656

typedef __attribute__((ext_vector_type(4))) float  f32x4;
typedef __attribute__((ext_vector_type(8))) short  short8;
typedef __attribute__((ext_vector_type(8))) unsigned short ushort8;
typedef __attribute__((ext_vector_type(4))) unsigned int uint4v;

__device__ __forceinline__ float bf2f(unsigned short u) {
    unsigned int x = ((unsigned int)u) << 16;
    return __builtin_bit_cast(float, x);
}
__device__ __forceinline__ unsigned short f2bf(float f) {
    unsigned int x = __builtin_bit_cast(unsigned int, f);
    unsigned int r = (x + 0x7fffu + ((x >> 16) & 1u)) >> 16;
    return (unsigned short)r;
}

// packed: relu(bf16x2(H) + bf16x2(S)) -> bf16x2 (truncation pack via v_perm)
__device__ __forceinline__ short8 packrelu8(ushort8 H8, ushort8 S8) {
    uint4v H = __builtin_bit_cast(uint4v, H8);
    uint4v S = __builtin_bit_cast(uint4v, S8);
    uint4v O;
#pragma unroll
    for (int d = 0; d < 4; ++d) {
        float hlo = __builtin_bit_cast(float, H[d] << 16);
        float hhi = __builtin_bit_cast(float, H[d] & 0xffff0000u);
        float slo = __builtin_bit_cast(float, S[d] << 16);
        float shi = __builtin_bit_cast(float, S[d] & 0xffff0000u);
        unsigned int rlo = __builtin_bit_cast(unsigned int, fmaxf(hlo + slo, 0.f));
        unsigned int rhi = __builtin_bit_cast(unsigned int, fmaxf(hhi + shi, 0.f));
        O[d] = __builtin_amdgcn_perm(rhi, rlo, 0x07060302u);
    }
    return __builtin_bit_cast(short8, O);
}

// ---- workspace layout (float offsets) ----
#define WS_PP    0u          // P' [36][1024] f32
#define WS_C1    36864u      // [1024] f32
#define WS_SH    37888u      // Sh bf16 [216][1024] -> 110592 f
#define WS_S3    148480u     // S3 bf16 [216][1024] -> 110592 f
#define WS_W2BF  259072u     // W2 bf16 [256][1024] -> 131072 f
#define WS_C2    390144u     // [256] f32
#define WS_W3BF  390400u     // W3 bf16 [784][256] -> 100352 f
#define WS_C3    490752u     // [16] f32
#define WS_XBF   490768u     // X bf16 [64][160] -> 5120 f
#define WS_SX2   495888u     // [64] f32
#define WS_E1T   495952u     // e1n^T [256 o][64 b] f32 -> 16384 f
#define WS_E2T   512336u     // e2n^T [1024 j][64 b] f32 -> 65536 f

#define OBS_SIZE (64*NNC)
#define DIST_OFF OBS_SIZE
#define LOSS_OFF (OBS_SIZE + 64*36)

// ---- decoder LDS (bytes), 32-code blocks:
// sE2p@0(512) sE2f@512(128) emL@640(10240) h3w@10880(4x2560=10240) h2L@21120(16384)
// total 37504 -> 4 blocks/CU
#define LDS_BYTES 37504

// ============================ K1: coalesced prep + conv/BN ============================
// blocks: [0,64) P'+c1 | [64,320) W2 | [320,336) W3 | 336 X | [337,401) conv+BN

__global__ void dvae_k1(const float* __restrict__ x,
                        const float* __restrict__ conv_w, const float* __restrict__ conv_b,
                        const float* __restrict__ ebn2_g, const float* __restrict__ ebn2_b,
                        const float* __restrict__ embeds, const float* __restrict__ dfc1_w,
                        const float* __restrict__ dfc1_b,
                        const float* __restrict__ dbn1_g, const float* __restrict__ dbn1_b,
                        const float* __restrict__ dbn1_rm, const float* __restrict__ dbn1_rv,
                        const float* __restrict__ dfc2_w, const float* __restrict__ dfc2_b,
                        const float* __restrict__ dbn2_g, const float* __restrict__ dbn2_b,
                        const float* __restrict__ dbn2_rm, const float* __restrict__ dbn2_rv,
                        const float* __restrict__ dct1_w, const float* __restrict__ dct1_b,
                        const float* __restrict__ dbn3_g, const float* __restrict__ dbn3_b,
                        const float* __restrict__ dbn3_rm, const float* __restrict__ dbn3_rv,
                        float* __restrict__ ws) {
    __shared__ float sbuf[12544];
    int bx = blockIdx.x, tid = threadIdx.x;
    if (bx < 64) {                       // ---- P' [36][1024] + c1 ----
        float* wtile = sbuf;             // [16][193]
        float* semb  = sbuf + 3088;      // [1152]
        int j0 = bx * 16;
        for (int e = tid; e < 16 * 192; e += 256)
            wtile[(e / 192) * 193 + (e % 192)] = dfc1_w[j0 * 192 + e];
        for (int e = tid; e < 1152; e += 256) semb[e] = embeds[e];
        __syncthreads();
        int jL = tid & 15, vk0 = tid >> 4;
        int j = j0 + jL;
        float s1 = dbn1_g[j] * rsqrtf(dbn1_rv[j] + EPSF);
        for (int vk = vk0; vk < 36; vk += 16) {
            int v = vk / 6;
            const float* wrow = &wtile[jL * 193 + v * 32];
            const float* ep = &semb[vk * 32];
            float dot = 0.f;
#pragma unroll
            for (int d = 0; d < 32; ++d) dot += wrow[d] * ep[d];
            ws[WS_PP + vk * 1024 + j] = s1 * dot;
        }
        if (tid < 16) {
            int jj = j0 + tid;
            float s = dbn1_g[jj] * rsqrtf(dbn1_rv[jj] + EPSF);
            ws[WS_C1 + jj] = s * dfc1_b[jj] + dbn1_b[jj] - dbn1_rm[jj] * s;
        }
    } else if (bx < 320) {               // ---- W2 bf16 + c2 ----
        int t = (bx - 64) * 256 + tid;
        int i = t >> 8, kq = (t & 255) * 4;
        float s2 = dbn2_g[i] * rsqrtf(dbn2_rv[i] + EPSF);
        float4 w = *(const float4*)(dfc2_w + i * 1024 + kq);
        unsigned short* dst = (unsigned short*)(ws + WS_W2BF) + i * 1024 + kq;
        dst[0] = f2bf(s2 * w.x); dst[1] = f2bf(s2 * w.y);
        dst[2] = f2bf(s2 * w.z); dst[3] = f2bf(s2 * w.w);
        if (kq == 0) ws[WS_C2 + i] = s2 * dfc2_b[i] + dbn2_b[i] - dbn2_rm[i] * s2;
    } else if (bx < 336) {               // ---- W3 bf16 + c3 (LDS transpose) ----
        int blk = bx - 320;
        for (int e = tid; e < 12544; e += 256) sbuf[e] = dct1_w[blk * 12544 + e];
        __syncthreads();
        unsigned short* W3 = (unsigned short*)(ws + WS_W3BF);
        for (int e = tid; e < 1568; e += 256) {
            int up = e >> 1, k8 = (e & 1) * 8;
            int o = up & 15, hw = up >> 4;
            float s3 = dbn3_g[o] * rsqrtf(dbn3_rv[o] + EPSF);
            ushort8 ov;
#pragma unroll
            for (int t2 = 0; t2 < 8; ++t2)
                ov[t2] = f2bf(s3 * sbuf[(k8 + t2) * 784 + o * 49 + hw]);
            *(ushort8*)(W3 + up * 256 + blk * 16 + k8) = ov;
        }
        if (blk == 0 && tid < 16) {
            float s = dbn3_g[tid] * rsqrtf(dbn3_rv[tid] + EPSF);
            ws[WS_C3 + tid] = s * dct1_b[tid] + dbn3_b[tid] - dbn3_rm[tid] * s;
        }
    } else if (bx == 336) {              // ---- X bf16 + sum(x^2) ----
        unsigned short* Xb = (unsigned short*)(ws + WS_XBF);
        if (tid < 64) {
            const float* xp = x + tid * 147;
            float s = 0.f;
            for (int qq = 0; qq < 147; ++qq) { float v = xp[qq]; s += v * v; }
            ws[WS_SX2 + tid] = s;
        }
        for (int e = tid; e < 64 * 160; e += 256) {
            int b = e / 160, col = e % 160;
            float v = 0.f;
            if (col < 147) { int hw = col / 3, c = col % 3; v = x[b * 147 + c * 49 + hw]; }
            Xb[e] = f2bf(v);
        }
    } else {                             // ---- conv + BN-train (x staged in LDS) ----
        int blk = bx - 337;
        for (int e = tid; e < 9408; e += 256) sbuf[e] = x[e];
        __syncthreads();
        int b = tid & 63;
        int oL = __builtin_amdgcn_readfirstlane(tid >> 6);
        int o = blk * 4 + oL;
        const float* wp = conv_w + o * 147;
        float acc = conv_b[o];
#pragma unroll 7
        for (int qq = 0; qq < 147; ++qq) acc += sbuf[b * 147 + qq] * wp[qq];
        float m = acc;
#pragma unroll
        for (int s = 1; s < 64; s <<= 1) m += __shfl_xor(m, s);
        m *= (1.f / 64.f);
        float d = acc - m;
        float var = d * d;
#pragma unroll
        for (int s = 1; s < 64; s <<= 1) var += __shfl_xor(var, s);
        var *= (1.f / 64.f);
        float y = ebn2_g[o] * d * rsqrtf(var + EPSF) + ebn2_b[o];
        ws[WS_E1T + o * 64 + b] = fmaxf(y, 0.f);
    }
}

// ============================ K2: Sh/S3 tables + fc1/BN ============================

__global__ void dvae_k2(const float* __restrict__ fc1_w, const float* __restrict__ fc1_b,
                        const float* __restrict__ ebn1_g, const float* __restrict__ ebn1_b,
                        float* __restrict__ ws) {
    int bx = blockIdx.x, tid = threadIdx.x;
    const float* Pp = ws + WS_PP;
    if (bx < 108) {
        int t = bx * 256 + tid;
        int gh = t >> 7, kg = (t & 127) * 8;
        int d0 = gh / 36, d1 = (gh / 6) % 6, d2 = gh % 6;
        const float* r0 = Pp + d0 * 1024 + kg;
        const float* r1 = Pp + (6 + d1) * 1024 + kg;
        const float* r2 = Pp + (12 + d2) * 1024 + kg;
        const float* cc = ws + WS_C1 + kg;
        ushort8 o;
#pragma unroll
        for (int e = 0; e < 8; ++e) o[e] = f2bf(cc[e] + r0[e] + r1[e] + r2[e]);
        *(ushort8*)((unsigned short*)(ws + WS_SH) + gh * 1024 + kg) = o;
    } else if (bx < 216) {
        int t = (bx - 108) * 256 + tid;
        int gl = t >> 7, kg = (t & 127) * 8;
        int d3 = gl / 36, d4 = (gl / 6) % 6, d5 = gl % 6;
        const float* r3 = Pp + (18 + d3) * 1024 + kg;
        const float* r4 = Pp + (24 + d4) * 1024 + kg;
        const float* r5 = Pp + (30 + d5) * 1024 + kg;
        ushort8 o;
#pragma unroll
        for (int e = 0; e < 8; ++e) o[e] = f2bf(r3[e] + r4[e] + r5[e]);
        *(ushort8*)((unsigned short*)(ws + WS_S3) + gl * 1024 + kg) = o;
    } else {
        int blk = bx - 216;
        int b = tid & 63;
        int jL = __builtin_amdgcn_readfirstlane(tid >> 6);
        int j = blk * 4 + jL;
        const float* e1 = ws + WS_E1T;
        const float* wp = fc1_w + j * 256;
        float acc = fc1_b[j];
#pragma unroll 8
        for (int o = 0; o < 256; ++o) acc += e1[o * 64 + b] * wp[o];
        float m = acc;
#pragma unroll
        for (int s = 1; s < 64; s <<= 1) m += __shfl_xor(m, s);
        m *= (1.f / 64.f);
        float d = acc - m;
        float var = d * d;
#pragma unroll
        for (int s = 1; s < 64; s <<= 1) var += __shfl_xor(var, s);
        var *= (1.f / 64.f);
        float y = ebn1_g[j] * d * rsqrtf(var + EPSF) + ebn1_b[j];
        ws[WS_E2T + j * 64 + b] = fmaxf(y, 0.f);
    }
}

// ============================ K3: fused decoder, 32 codes/block (4 blocks/CU) ============================

__launch_bounds__(256, 4)
__global__ void dvae_k3(const unsigned short* __restrict__ Sh,
                        const unsigned short* __restrict__ S3g,
                        const unsigned short* __restrict__ W2,
                        const float* __restrict__ c2g,
                        const unsigned short* __restrict__ W3,
                        const float* __restrict__ c3g,
                        const float* __restrict__ d2wg,
                        const float* __restrict__ d2bg,
                        const unsigned short* __restrict__ Xg,
                        const float* __restrict__ sx2g,
                        const float* __restrict__ e2T,
                        const float* __restrict__ fc2_w,
                        const float* __restrict__ fc2_b,
                        float* __restrict__ out) {
    extern __shared__ char sm[];
    int tid = threadIdx.x;

    if (blockIdx.x == 0) {
        // ---- logits via 64-wide LDS chunks + softmax + entropy (fits 34.8 KB) ----
        float* wch = (float*)sm;              // [36][64]
        float* ech = (float*)(sm + 9216);     // [64][64]
        float* LG  = (float*)(sm + 25600);    // [64][36]
        int b = tid & 63;
        int wvU = __builtin_amdgcn_readfirstlane(tid >> 6);
        float accv[9];
#pragma unroll
        for (int it = 0; it < 9; ++it) accv[it] = 0.f;
        for (int ch = 0; ch < 16; ++ch) {
            __syncthreads();
            for (int e = tid; e < 36 * 64; e += 256)
                wch[e] = fc2_w[(e >> 6) * 1024 + ch * 64 + (e & 63)];
            for (int e = tid; e < 64 * 64; e += 256)
                ech[e] = e2T[(ch * 64 + (e >> 6)) * 64 + (e & 63)];
            __syncthreads();
            for (int jl = 0; jl < 64; ++jl) {
                float ev = ech[jl * 64 + b];
#pragma unroll
                for (int it = 0; it < 9; ++it)
                    accv[it] += ev * wch[(wvU + it * 4) * 64 + jl];
            }
        }
#pragma unroll
        for (int it = 0; it < 9; ++it) {
            int o = wvU + it * 4;
            LG[b * 36 + o] = accv[it] + fc2_b[o];
        }
        __syncthreads();
        if (tid < 64) {
            float loss = 0.f;
#pragma unroll
            for (int v = 0; v < 6; ++v) {
                float mx = -1e30f;
#pragma unroll
                for (int k = 0; k < 6; ++k) mx = fmaxf(mx, LG[tid * 36 + v * 6 + k]);
                float s = 0.f, ex[6];
#pragma unroll
                for (int k = 0; k < 6; ++k) { ex[k] = expf(LG[tid * 36 + v * 6 + k] - mx); s += ex[k]; }
                float inv = 1.f / s;
#pragma unroll
                for (int k = 0; k < 6; ++k) {
                    float dd = ex[k] * inv;
                    out[DIST_OFF + tid * 36 + v * 6 + k] = dd;
                    loss += dd * logf(dd + 1e-10f);
                }
            }
            out[LOSS_OFF + tid] = 0.1f * loss;
        }
        return;
    }

    // ---- decoder: 32 codes per block ----
    int wv = tid >> 6, lane = tid & 63, l15 = lane & 15, q = lane >> 4;
    int nbase = (blockIdx.x - 1) * 32;
    float* sE2p = (float*)(sm + 0);                       // [4][32]
    float* sE2f = (float*)(sm + 512);                     // [32]
    unsigned short* emL = (unsigned short*)(sm + 640);    // [32][160]
    float* h3w = (float*)(sm + 10880 + wv * 2560);        // per-wave [32][20] f32
    unsigned short* h2L = (unsigned short*)(sm + 21120);  // [32 kb][32 m][8]

    // ---------------- phase 1: barrier-free, A in registers (mt=0,1) ----------------
    f32x4 acc[2][4];
#pragma unroll
    for (int a = 0; a < 2; ++a)
#pragma unroll
        for (int b = 0; b < 4; ++b) acc[a][b] = (f32x4){0.f, 0.f, 0.f, 0.f};

    const unsigned short* pSh[2];
    const unsigned short* pS3[2];
#pragma unroll
    for (int mt = 0; mt < 2; ++mt) {
        int nm = nbase + mt * 16 + l15;
        int gh = nm / 216;
        int r216 = nm - gh * 216;
        pSh[mt] = Sh + gh * 1024 + q * 8;
        pS3[mt] = S3g + r216 * 1024 + q * 8;
    }
    const unsigned short* bbase = W2 + (wv * 64 + l15) * 1024 + q * 8;

    ushort8 sa[2], sb[2];
    short8 bpre[4];
#pragma unroll
    for (int mt = 0; mt < 2; ++mt) { sa[mt] = *(const ushort8*)(pSh[mt]); sb[mt] = *(const ushort8*)(pS3[mt]); }
#pragma unroll
    for (int j = 0; j < 4; ++j) bpre[j] = *(const short8*)(bbase + j * 16384);

#pragma unroll 2
    for (int s = 0; s < 32; ++s) {
        short8 af[2];
#pragma unroll
        for (int mt = 0; mt < 2; ++mt) af[mt] = packrelu8(sa[mt], sb[mt]);
        short8 bcur[4];
#pragma unroll
        for (int j = 0; j < 4; ++j) bcur[j] = bpre[j];
        if (s < 31) {
            int off = (s + 1) * 32;
#pragma unroll
            for (int mt = 0; mt < 2; ++mt) {
                sa[mt] = *(const ushort8*)(pSh[mt] + off);
                sb[mt] = *(const ushort8*)(pS3[mt] + off);
            }
#pragma unroll
            for (int j = 0; j < 4; ++j) bpre[j] = *(const short8*)(bbase + j * 16384 + off);
        }
#pragma unroll
        for (int mt = 0; mt < 2; ++mt)
#pragma unroll
            for (int j = 0; j < 4; ++j)
                acc[mt][j] = __builtin_amdgcn_mfma_f32_16x16x32_bf16(af[mt], bcur[j], acc[mt][j], 0, 0, 0);
    }
    // h2 epilogue -> h2L bf16 [kb=i>>3][m][i&7]
#pragma unroll
    for (int j = 0; j < 4; ++j) {
        int i = wv * 64 + j * 16 + l15;
        float cc = c2g[i];
#pragma unroll
        for (int mt = 0; mt < 2; ++mt)
#pragma unroll
            for (int r = 0; r < 4; ++r) {
                int m = mt * 16 + q * 4 + r;
                h2L[((i >> 3) * 32 + m) * 8 + (i & 7)] = f2bf(fmaxf(acc[mt][j][r] + cc, 0.f));
            }
    }
    __syncthreads();   // barrier 1: h2L complete

    // ---------------- phase 2: GEMM3 + channel projection ----------------
    float c3v = c3g[l15];
    float db0 = d2bg[0], db1 = d2bg[1], db2 = d2bg[2];
    float dw0[16], dw1[16], dw2[16];
#pragma unroll
    for (int o = 0; o < 16; ++o) {
        dw0[o] = d2wg[o * 3 + 0]; dw1[o] = d2wg[o * 3 + 1]; dw2[o] = d2wg[o * 3 + 2];
    }
    float sE2a = 0.f;
    for (int c = wv; c < 13; c += 4) {
        int hw0 = c * 4;
        f32x4 a2[2][4];
#pragma unroll
        for (int a = 0; a < 2; ++a)
#pragma unroll
            for (int b = 0; b < 4; ++b) a2[a][b] = (f32x4){0.f, 0.f, 0.f, 0.f};
        const unsigned short* b3[4];
#pragma unroll
        for (int j = 0; j < 4; ++j) {
            int hw = hw0 + j; if (hw > 48) hw = 48;
            b3[j] = W3 + (hw * 16 + l15) * 256 + q * 8;
        }
        short8 bpre2[4];
#pragma unroll
        for (int j = 0; j < 4; ++j) bpre2[j] = *(const short8*)(b3[j]);
#pragma unroll
        for (int s = 0; s < 8; ++s) {
            short8 bcur[4];
#pragma unroll
            for (int j = 0; j < 4; ++j) bcur[j] = bpre2[j];
            if (s < 7) {
#pragma unroll
                for (int j = 0; j < 4; ++j) bpre2[j] = *(const short8*)(b3[j] + (s + 1) * 32);
            }
            short8 af[2];
#pragma unroll
            for (int mt = 0; mt < 2; ++mt)
                af[mt] = *(const short8*)(h2L + ((s * 4 + q) * 32 + mt * 16 + l15) * 8);
#pragma unroll
            for (int mt = 0; mt < 2; ++mt)
#pragma unroll
                for (int j = 0; j < 4; ++j)
                    a2[mt][j] = __builtin_amdgcn_mfma_f32_16x16x32_bf16(af[mt], bcur[j], a2[mt][j], 0, 0, 0);
        }
#pragma unroll
        for (int j = 0; j < 4; ++j) {
            int hw = hw0 + j;
            if (hw <= 48) {
#pragma unroll
                for (int mt = 0; mt < 2; ++mt)
#pragma unroll
                    for (int r = 0; r < 4; ++r)
                        h3w[(mt * 16 + q * 4 + r) * 20 + l15] = fmaxf(a2[mt][j][r] + c3v, 0.f);
                if (lane < 32) {
                    int m = lane;
                    float hvv[16];
#pragma unroll
                    for (int g = 0; g < 4; ++g) {
                        f32x4 tv = *(const f32x4*)(h3w + m * 20 + g * 4);
                        hvv[g * 4 + 0] = tv[0]; hvv[g * 4 + 1] = tv[1];
                        hvv[g * 4 + 2] = tv[2]; hvv[g * 4 + 3] = tv[3];
                    }
                    float e0 = db0, e1 = db1, e2 = db2;
#pragma unroll
                    for (int o = 0; o < 16; ++o) {
                        e0 += hvv[o] * dw0[o]; e1 += hvv[o] * dw1[o]; e2 += hvv[o] * dw2[o];
                    }
                    unsigned short u0 = f2bf(e0), u1 = f2bf(e1), u2 = f2bf(e2);
                    float f0 = bf2f(u0), f1 = bf2f(u1), f2v = bf2f(u2);
                    sE2a += f0 * f0 + f1 * f1 + f2v * f2v;
                    emL[m * 160 + hw * 3 + 0] = u0;
                    emL[m * 160 + hw * 3 + 1] = u1;
                    emL[m * 160 + hw * 3 + 2] = u2;
                }
            }
        }
    }
    if (lane < 32) sE2p[wv * 32 + lane] = sE2a;
    for (int e = tid; e < 32 * 13; e += 256) emL[(e / 13) * 160 + 147 + (e % 13)] = 0;
    __syncthreads();   // barrier 2: emL + sE2p complete
    if (tid < 32) sE2f[tid] = sE2p[tid] + sE2p[32 + tid] + sE2p[64 + tid] + sE2p[96 + tid];
    __syncthreads();

    // ---------------- phase 3: obs = X @ em^T ----------------
    f32x4 aO[2];
#pragma unroll
    for (int j = 0; j < 2; ++j) aO[j] = (f32x4){0.f, 0.f, 0.f, 0.f};
    const unsigned short* xrow = Xg + (wv * 16 + l15) * 160 + q * 8;
#pragma unroll
    for (int s = 0; s < 5; ++s) {
        short8 af = *(const short8*)(xrow + s * 32);
#pragma unroll
        for (int j = 0; j < 2; ++j) {
            short8 bfv = *(const short8*)(emL + (j * 16 + l15) * 160 + s * 32 + q * 8);
            aO[j] = __builtin_amdgcn_mfma_f32_16x16x32_bf16(af, bfv, aO[j], 0, 0, 0);
        }
    }
    int b0 = wv * 16 + q * 4;
    float sxv[4];
#pragma unroll
    for (int r = 0; r < 4; ++r) sxv[r] = sx2g[b0 + r];
#pragma unroll
    for (int j = 0; j < 2; ++j) {
        int n = nbase + j * 16 + l15;
        float he = 0.5f * sE2f[j * 16 + l15];
#pragma unroll
        for (int r = 0; r < 4; ++r)
            out[(size_t)(b0 + r) * NNC + n] = aO[j][r] - he - 0.5f * sxv[r];
    }
}

// ============================ launcher ============================

extern "C" void kernel_launch(void* const* d_in, const int* in_sizes, int n_in,
                              void* d_out, int out_size, void* d_ws, size_t ws_size,
                              hipStream_t stream) {
    const float* x       = (const float*)d_in[0];
    const float* conv_w  = (const float*)d_in[1];
    const float* conv_b  = (const float*)d_in[2];
    const float* ebn2_g  = (const float*)d_in[3];
    const float* ebn2_b  = (const float*)d_in[4];
    const float* fc1_w   = (const float*)d_in[5];
    const float* fc1_b   = (const float*)d_in[6];
    const float* ebn1_g  = (const float*)d_in[7];
    const float* ebn1_b  = (const float*)d_in[8];
    const float* fc2_w   = (const float*)d_in[9];
    const float* fc2_b   = (const float*)d_in[10];
    const float* embeds  = (const float*)d_in[11];
    const float* dfc1_w  = (const float*)d_in[12];
    const float* dfc1_b  = (const float*)d_in[13];
    const float* dbn1_g  = (const float*)d_in[14];
    const float* dbn1_b  = (const float*)d_in[15];
    const float* dbn1_rm = (const float*)d_in[16];
    const float* dbn1_rv = (const float*)d_in[17];
    const float* dfc2_w  = (const float*)d_in[18];
    const float* dfc2_b  = (const float*)d_in[19];
    const float* dbn2_g  = (const float*)d_in[20];
    const float* dbn2_b  = (const float*)d_in[21];
    const float* dbn2_rm = (const float*)d_in[22];
    const float* dbn2_rv = (const float*)d_in[23];
    const float* dct1_w  = (const float*)d_in[24];
    const float* dct1_b  = (const float*)d_in[25];
    const float* dbn3_g  = (const float*)d_in[26];
    const float* dbn3_b  = (const float*)d_in[27];
    const float* dbn3_rm = (const float*)d_in[28];
    const float* dbn3_rv = (const float*)d_in[29];
    const float* dct2_w  = (const float*)d_in[30];
    const float* dct2_b  = (const float*)d_in[31];

    float* ws  = (float*)d_ws;
    float* out = (float*)d_out;

    dvae_k1<<<401, 256, 0, stream>>>(x, conv_w, conv_b, ebn2_g, ebn2_b,
                                     embeds, dfc1_w, dfc1_b, dbn1_g, dbn1_b, dbn1_rm, dbn1_rv,
                                     dfc2_w, dfc2_b, dbn2_g, dbn2_b, dbn2_rm, dbn2_rv,
                                     dct1_w, dct1_b, dbn3_g, dbn3_b, dbn3_rm, dbn3_rv, ws);
    dvae_k2<<<472, 256, 0, stream>>>(fc1_w, fc1_b, ebn1_g, ebn1_b, ws);

    dvae_k3<<<NNC / 32 + 1, 256, LDS_BYTES, stream>>>(
        (const unsigned short*)(ws + WS_SH), (const unsigned short*)(ws + WS_S3),
        (const unsigned short*)(ws + WS_W2BF), ws + WS_C2,
        (const unsigned short*)(ws + WS_W3BF), ws + WS_C3,
        dct2_w, dct2_b,
        (const unsigned short*)(ws + WS_XBF), ws + WS_SX2,
        ws + WS_E2T, fc2_w, fc2_b, out);
}

// Round 11
// 274.029 us; speedup vs baseline: 1.7575x; 1.3688x over previous
//
#include <hip/hip_runtime.h>
#include <math.h>

#define EPSF 1e-5f
#define NNC 46656

typedef __attribute__((ext_vector_type(4))) float  f32x4;
typedef __attribute__((ext_vector_type(8))) short  short8;
typedef __attribute__((ext_vector_type(8))) unsigned short ushort8;
typedef __attribute__((ext_vector_type(4))) unsigned int uint4v;

__device__ __forceinline__ float bf2f(unsigned short u) {
    unsigned int x = ((unsigned int)u) << 16;
    return __builtin_bit_cast(float, x);
}
__device__ __forceinline__ unsigned short f2bf(float f) {
    unsigned int x = __builtin_bit_cast(unsigned int, f);
    unsigned int r = (x + 0x7fffu + ((x >> 16) & 1u)) >> 16;
    return (unsigned short)r;
}

// packed: relu(bf16x2(H) + bf16x2(S)) -> bf16x2 (truncation pack via v_perm)
__device__ __forceinline__ short8 packrelu8(ushort8 H8, ushort8 S8) {
    uint4v H = __builtin_bit_cast(uint4v, H8);
    uint4v S = __builtin_bit_cast(uint4v, S8);
    uint4v O;
#pragma unroll
    for (int d = 0; d < 4; ++d) {
        float hlo = __builtin_bit_cast(float, H[d] << 16);
        float hhi = __builtin_bit_cast(float, H[d] & 0xffff0000u);
        float slo = __builtin_bit_cast(float, S[d] << 16);
        float shi = __builtin_bit_cast(float, S[d] & 0xffff0000u);
        unsigned int rlo = __builtin_bit_cast(unsigned int, fmaxf(hlo + slo, 0.f));
        unsigned int rhi = __builtin_bit_cast(unsigned int, fmaxf(hhi + shi, 0.f));
        O[d] = __builtin_amdgcn_perm(rhi, rlo, 0x07060302u);
    }
    return __builtin_bit_cast(short8, O);
}

// ---- workspace layout (float offsets) ----
#define WS_SH    37888u      // Sh bf16 [216][1024] -> 110592 f
#define WS_S3    148480u     // S3 bf16 [216][1024] -> 110592 f
#define WS_W2BF  259072u     // W2 bf16 [256][1024] -> 131072 f
#define WS_C2    390144u     // [256] f32
#define WS_W3BF  390400u     // W3 bf16 [784][256] -> 100352 f
#define WS_C3    490752u     // [16] f32
#define WS_XBF   490768u     // X bf16 [64][160] -> 5120 f
#define WS_SX2   495888u     // [64] f32
#define WS_E1T   495952u     // e1n^T [256 o][64 b] f32 -> 16384 f
#define WS_E2T   512336u     // e2n^T [1024 j][64 b] f32 -> 65536 f
#define WS_FLAG  577872u     // int completion flag for fc1 blocks

#define OBS_SIZE (64*NNC)
#define DIST_OFF OBS_SIZE
#define LOSS_OFF (OBS_SIZE + 64*36)

#define LDS_BYTES 75008

// ============================ K1: all prep + tables + conv/BN ============================
// blocks: [0,64) P'+Sh/S3 tables | [64,320) W2 | [320,336) W3 | 336 X+flag | [337,401) conv+BN

__global__ void dvae_k1(const float* __restrict__ x,
                        const float* __restrict__ conv_w, const float* __restrict__ conv_b,
                        const float* __restrict__ ebn2_g, const float* __restrict__ ebn2_b,
                        const float* __restrict__ embeds, const float* __restrict__ dfc1_w,
                        const float* __restrict__ dfc1_b,
                        const float* __restrict__ dbn1_g, const float* __restrict__ dbn1_b,
                        const float* __restrict__ dbn1_rm, const float* __restrict__ dbn1_rv,
                        const float* __restrict__ dfc2_w, const float* __restrict__ dfc2_b,
                        const float* __restrict__ dbn2_g, const float* __restrict__ dbn2_b,
                        const float* __restrict__ dbn2_rm, const float* __restrict__ dbn2_rv,
                        const float* __restrict__ dct1_w, const float* __restrict__ dct1_b,
                        const float* __restrict__ dbn3_g, const float* __restrict__ dbn3_b,
                        const float* __restrict__ dbn3_rm, const float* __restrict__ dbn3_rv,
                        float* __restrict__ ws) {
    __shared__ float sbuf[12544];
    int bx = blockIdx.x, tid = threadIdx.x;
    if (bx < 64) {                       // ---- P' (LDS) -> Sh/S3 slices directly ----
        float* wtile = sbuf;             // [16][193] = 3088
        float* semb  = sbuf + 3088;      // [1152]
        float* Pt    = sbuf + 4240;      // [36][20] = 720
        float* c1s   = sbuf + 4960;      // [16]
        int j0 = bx * 16;
        for (int e = tid; e < 16 * 192; e += 256)
            wtile[(e / 192) * 193 + (e % 192)] = dfc1_w[j0 * 192 + e];
        for (int e = tid; e < 1152; e += 256) semb[e] = embeds[e];
        __syncthreads();
        for (int e = tid; e < 576; e += 256) {
            int vk = e >> 4, jL = e & 15;
            int v = vk / 6;
            int j = j0 + jL;
            const float* wrow = &wtile[jL * 193 + v * 32];
            const float* ep = &semb[vk * 32];
            float dot = 0.f;
#pragma unroll
            for (int d = 0; d < 32; ++d) dot += wrow[d] * ep[d];
            float s1 = dbn1_g[j] * rsqrtf(dbn1_rv[j] + EPSF);
            Pt[vk * 20 + jL] = s1 * dot;
        }
        if (tid < 16) {
            int j = j0 + tid;
            float s = dbn1_g[j] * rsqrtf(dbn1_rv[j] + EPSF);
            c1s[tid] = s * dfc1_b[j] + dbn1_b[j] - dbn1_rm[j] * s;
        }
        __syncthreads();
        unsigned short* Sh = (unsigned short*)(ws + WS_SH);
        unsigned short* S3 = (unsigned short*)(ws + WS_S3);
        for (int e = tid; e < 216 * 16; e += 256) {
            int gh = e >> 4, jL = e & 15;
            int d0 = gh / 36, d1 = (gh / 6) % 6, d2 = gh % 6;
            float vh = c1s[jL] + Pt[d0 * 20 + jL] + Pt[(6 + d1) * 20 + jL] + Pt[(12 + d2) * 20 + jL];
            float vs = Pt[(18 + d0) * 20 + jL] + Pt[(24 + d1) * 20 + jL] + Pt[(30 + d2) * 20 + jL];
            Sh[gh * 1024 + j0 + jL] = f2bf(vh);
            S3[gh * 1024 + j0 + jL] = f2bf(vs);
        }
    } else if (bx < 320) {               // ---- W2 bf16 + c2 ----
        int t = (bx - 64) * 256 + tid;
        int i = t >> 8, kq = (t & 255) * 4;
        float s2 = dbn2_g[i] * rsqrtf(dbn2_rv[i] + EPSF);
        float4 w = *(const float4*)(dfc2_w + i * 1024 + kq);
        unsigned short* dst = (unsigned short*)(ws + WS_W2BF) + i * 1024 + kq;
        dst[0] = f2bf(s2 * w.x); dst[1] = f2bf(s2 * w.y);
        dst[2] = f2bf(s2 * w.z); dst[3] = f2bf(s2 * w.w);
        if (kq == 0) ws[WS_C2 + i] = s2 * dfc2_b[i] + dbn2_b[i] - dbn2_rm[i] * s2;
    } else if (bx < 336) {               // ---- W3 bf16 + c3 (LDS transpose) ----
        int blk = bx - 320;
        for (int e = tid; e < 12544; e += 256) sbuf[e] = dct1_w[blk * 12544 + e];
        __syncthreads();
        unsigned short* W3 = (unsigned short*)(ws + WS_W3BF);
        for (int e = tid; e < 1568; e += 256) {
            int up = e >> 1, k8 = (e & 1) * 8;
            int o = up & 15, hw = up >> 4;
            float s3 = dbn3_g[o] * rsqrtf(dbn3_rv[o] + EPSF);
            ushort8 ov;
#pragma unroll
            for (int t2 = 0; t2 < 8; ++t2)
                ov[t2] = f2bf(s3 * sbuf[(k8 + t2) * 784 + o * 49 + hw]);
            *(ushort8*)(W3 + up * 256 + blk * 16 + k8) = ov;
        }
        if (blk == 0 && tid < 16) {
            float s = dbn3_g[tid] * rsqrtf(dbn3_rv[tid] + EPSF);
            ws[WS_C3 + tid] = s * dct1_b[tid] + dbn3_b[tid] - dbn3_rm[tid] * s;
        }
    } else if (bx == 336) {              // ---- X bf16 + sum(x^2) + flag zero ----
        unsigned short* Xb = (unsigned short*)(ws + WS_XBF);
        if (tid == 0) *(int*)(ws + WS_FLAG) = 0;
        if (tid < 64) {
            const float* xp = x + tid * 147;
            float s = 0.f;
            for (int qq = 0; qq < 147; ++qq) { float v = xp[qq]; s += v * v; }
            ws[WS_SX2 + tid] = s;
        }
        for (int e = tid; e < 64 * 160; e += 256) {
            int b = e / 160, col = e % 160;
            float v = 0.f;
            if (col < 147) { int hw = col / 3, c = col % 3; v = x[b * 147 + c * 49 + hw]; }
            Xb[e] = f2bf(v);
        }
    } else {                             // ---- conv + BN-train (x staged in LDS) ----
        int blk = bx - 337;
        for (int e = tid; e < 9408; e += 256) sbuf[e] = x[e];
        __syncthreads();
        int b = tid & 63;
        int oL = __builtin_amdgcn_readfirstlane(tid >> 6);
        int o = blk * 4 + oL;
        const float* wp = conv_w + o * 147;
        float acc = conv_b[o];
#pragma unroll 7
        for (int qq = 0; qq < 147; ++qq) acc += sbuf[b * 147 + qq] * wp[qq];
        float m = acc;
#pragma unroll
        for (int s = 1; s < 64; s <<= 1) m += __shfl_xor(m, s);
        m *= (1.f / 64.f);
        float d = acc - m;
        float var = d * d;
#pragma unroll
        for (int s = 1; s < 64; s <<= 1) var += __shfl_xor(var, s);
        var *= (1.f / 64.f);
        float y = ebn2_g[o] * d * rsqrtf(var + EPSF) + ebn2_b[o];
        ws[WS_E1T + o * 64 + b] = fmaxf(y, 0.f);
    }
}

// ============================ K3: fc1 blocks + logits (spin) + decoder ============================
// blocks: [0,256) fc1+BN -> e2T, signal flag | 256 logits (spin on flag) | [257,986) decoder

__launch_bounds__(256, 2)
__global__ void dvae_k3(const unsigned short* __restrict__ Sh,
                        const unsigned short* __restrict__ S3g,
                        const unsigned short* __restrict__ W2,
                        const float* __restrict__ c2g,
                        const unsigned short* __restrict__ W3,
                        const float* __restrict__ c3g,
                        const float* __restrict__ d2wg,
                        const float* __restrict__ d2bg,
                        const unsigned short* __restrict__ Xg,
                        const float* __restrict__ sx2g,
                        const float* __restrict__ fc1_w, const float* __restrict__ fc1_b,
                        const float* __restrict__ ebn1_g, const float* __restrict__ ebn1_b,
                        const float* __restrict__ e1T,
                        float* __restrict__ e2T,
                        int* __restrict__ flag,
                        const float* __restrict__ fc2_w,
                        const float* __restrict__ fc2_b,
                        float* __restrict__ out) {
    extern __shared__ char sm[];
    int tid = threadIdx.x;

    if (blockIdx.x < 256) {
        // ---- fc1 + BN-train -> e2T, then signal ----
        int blk = blockIdx.x;
        int b = tid & 63;
        int jL = __builtin_amdgcn_readfirstlane(tid >> 6);
        int j = blk * 4 + jL;
        const float* wp = fc1_w + j * 256;
        float acc = fc1_b[j];
#pragma unroll 8
        for (int o = 0; o < 256; ++o) acc += e1T[o * 64 + b] * wp[o];
        float m = acc;
#pragma unroll
        for (int s = 1; s < 64; s <<= 1) m += __shfl_xor(m, s);
        m *= (1.f / 64.f);
        float d = acc - m;
        float var = d * d;
#pragma unroll
        for (int s = 1; s < 64; s <<= 1) var += __shfl_xor(var, s);
        var *= (1.f / 64.f);
        float y = ebn1_g[j] * d * rsqrtf(var + EPSF) + ebn1_b[j];
        e2T[j * 64 + b] = fmaxf(y, 0.f);
        __syncthreads();
        if (tid == 0) { __threadfence(); atomicAdd(flag, 1); }
        return;
    }

    if (blockIdx.x == 256) {
        // ---- logits: wait for fc1, then LDS-staged GEMM + softmax + entropy ----
        if (tid == 0) {
            while (atomicAdd(flag, 0) < 256) __builtin_amdgcn_s_sleep(8);
        }
        __syncthreads();
        float* wch = (float*)sm;              // [36][128]
        float* ech = (float*)(sm + 18432);    // [128][64]
        float* LG  = (float*)(sm + 51200);    // [64][36]
        int b = tid & 63;
        int wvU = __builtin_amdgcn_readfirstlane(tid >> 6);
        float accv[9];
#pragma unroll
        for (int it = 0; it < 9; ++it) accv[it] = 0.f;
        for (int ch = 0; ch < 8; ++ch) {
            __syncthreads();
            for (int e = tid; e < 36 * 128; e += 256)
                wch[e] = fc2_w[(e >> 7) * 1024 + ch * 128 + (e & 127)];
            for (int e = tid; e < 128 * 64; e += 256)
                ech[e] = e2T[(ch * 128 + (e >> 6)) * 64 + (e & 63)];
            __syncthreads();
            for (int jl = 0; jl < 128; ++jl) {
                float ev = ech[jl * 64 + b];
#pragma unroll
                for (int it = 0; it < 9; ++it)
                    accv[it] += ev * wch[(wvU + it * 4) * 128 + jl];
            }
        }
#pragma unroll
        for (int it = 0; it < 9; ++it) {
            int o = wvU + it * 4;
            LG[b * 36 + o] = accv[it] + fc2_b[o];
        }
        __syncthreads();
        if (tid < 64) {
            float loss = 0.f;
#pragma unroll
            for (int v = 0; v < 6; ++v) {
                float mx = -1e30f;
#pragma unroll
                for (int k = 0; k < 6; ++k) mx = fmaxf(mx, LG[tid * 36 + v * 6 + k]);
                float s = 0.f, ex[6];
#pragma unroll
                for (int k = 0; k < 6; ++k) { ex[k] = expf(LG[tid * 36 + v * 6 + k] - mx); s += ex[k]; }
                float inv = 1.f / s;
#pragma unroll
                for (int k = 0; k < 6; ++k) {
                    float dd = ex[k] * inv;
                    out[DIST_OFF + tid * 36 + v * 6 + k] = dd;
                    loss += dd * logf(dd + 1e-10f);
                }
            }
            out[LOSS_OFF + tid] = 0.1f * loss;
        }
        return;
    }

    // ---- decoder (R8 verbatim) ----
    int wv = tid >> 6, lane = tid & 63, l15 = lane & 15, q = lane >> 4;
    int nbase = (blockIdx.x - 257) * 64;
    float* sE2p = (float*)(sm + 0);
    float* sE2f = (float*)(sm + 1024);
    unsigned short* emL = (unsigned short*)(sm + 1280);   // [64][160]
    float* h3w = (float*)(sm + 21760 + wv * 5120);        // per-wave [64][20] f32
    unsigned short* h2L = (unsigned short*)(sm + 42240);  // [32 kb][64 m][8]

    f32x4 acc[4][4];
#pragma unroll
    for (int a = 0; a < 4; ++a)
#pragma unroll
        for (int b = 0; b < 4; ++b) acc[a][b] = (f32x4){0.f, 0.f, 0.f, 0.f};

    const unsigned short* pSh[4];
    const unsigned short* pS3[4];
#pragma unroll
    for (int mt = 0; mt < 4; ++mt) {
        int nm = nbase + mt * 16 + l15;
        int gh = nm / 216;
        int r216 = nm - gh * 216;
        pSh[mt] = Sh + gh * 1024 + q * 8;
        pS3[mt] = S3g + r216 * 1024 + q * 8;
    }
    const unsigned short* bbase = W2 + (wv * 64 + l15) * 1024 + q * 8;

    ushort8 sa[4], sb[4];
    short8 bpre[4];
#pragma unroll
    for (int mt = 0; mt < 4; ++mt) { sa[mt] = *(const ushort8*)(pSh[mt]); sb[mt] = *(const ushort8*)(pS3[mt]); }
#pragma unroll
    for (int j = 0; j < 4; ++j) bpre[j] = *(const short8*)(bbase + j * 16384);

#pragma unroll 2
    for (int s = 0; s < 32; ++s) {
        short8 af[4];
#pragma unroll
        for (int mt = 0; mt < 4; ++mt) af[mt] = packrelu8(sa[mt], sb[mt]);
        short8 bcur[4];
#pragma unroll
        for (int j = 0; j < 4; ++j) bcur[j] = bpre[j];
        if (s < 31) {
            int off = (s + 1) * 32;
#pragma unroll
            for (int mt = 0; mt < 4; ++mt) {
                sa[mt] = *(const ushort8*)(pSh[mt] + off);
                sb[mt] = *(const ushort8*)(pS3[mt] + off);
            }
#pragma unroll
            for (int j = 0; j < 4; ++j) bpre[j] = *(const short8*)(bbase + j * 16384 + off);
        }
#pragma unroll
        for (int mt = 0; mt < 4; ++mt)
#pragma unroll
            for (int j = 0; j < 4; ++j)
                acc[mt][j] = __builtin_amdgcn_mfma_f32_16x16x32_bf16(af[mt], bcur[j], acc[mt][j], 0, 0, 0);
    }
#pragma unroll
    for (int j = 0; j < 4; ++j) {
        int i = wv * 64 + j * 16 + l15;
        float cc = c2g[i];
#pragma unroll
        for (int mt = 0; mt < 4; ++mt)
#pragma unroll
            for (int r = 0; r < 4; ++r) {
                int m = mt * 16 + q * 4 + r;
                h2L[((i >> 3) * 64 + m) * 8 + (i & 7)] = f2bf(fmaxf(acc[mt][j][r] + cc, 0.f));
            }
    }
    __syncthreads();

    float c3v = c3g[l15];
    float db0 = d2bg[0], db1 = d2bg[1], db2 = d2bg[2];
    float dw0[16], dw1[16], dw2[16];
#pragma unroll
    for (int o = 0; o < 16; ++o) {
        dw0[o] = d2wg[o * 3 + 0]; dw1[o] = d2wg[o * 3 + 1]; dw2[o] = d2wg[o * 3 + 2];
    }
    float sE2a = 0.f;
    for (int c = wv; c < 13; c += 4) {
        int hw0 = c * 4;
        f32x4 a2[4][4];
#pragma unroll
        for (int a = 0; a < 4; ++a)
#pragma unroll
            for (int b = 0; b < 4; ++b) a2[a][b] = (f32x4){0.f, 0.f, 0.f, 0.f};
        const unsigned short* b3[4];
#pragma unroll
        for (int j = 0; j < 4; ++j) {
            int hw = hw0 + j; if (hw > 48) hw = 48;
            b3[j] = W3 + (hw * 16 + l15) * 256 + q * 8;
        }
        short8 bpre2[4];
#pragma unroll
        for (int j = 0; j < 4; ++j) bpre2[j] = *(const short8*)(b3[j]);
#pragma unroll
        for (int s = 0; s < 8; ++s) {
            short8 bcur[4];
#pragma unroll
            for (int j = 0; j < 4; ++j) bcur[j] = bpre2[j];
            if (s < 7) {
#pragma unroll
                for (int j = 0; j < 4; ++j) bpre2[j] = *(const short8*)(b3[j] + (s + 1) * 32);
            }
            short8 af[4];
#pragma unroll
            for (int mt = 0; mt < 4; ++mt)
                af[mt] = *(const short8*)(h2L + ((s * 4 + q) * 64 + mt * 16 + l15) * 8);
#pragma unroll
            for (int mt = 0; mt < 4; ++mt)
#pragma unroll
                for (int j = 0; j < 4; ++j)
                    a2[mt][j] = __builtin_amdgcn_mfma_f32_16x16x32_bf16(af[mt], bcur[j], a2[mt][j], 0, 0, 0);
        }
#pragma unroll
        for (int j = 0; j < 4; ++j) {
            int hw = hw0 + j;
            if (hw <= 48) {
#pragma unroll
                for (int mt = 0; mt < 4; ++mt)
#pragma unroll
                    for (int r = 0; r < 4; ++r)
                        h3w[(mt * 16 + q * 4 + r) * 20 + l15] = fmaxf(a2[mt][j][r] + c3v, 0.f);
                float hvv[16];
#pragma unroll
                for (int g = 0; g < 4; ++g) {
                    f32x4 tv = *(const f32x4*)(h3w + lane * 20 + g * 4);
                    hvv[g * 4 + 0] = tv[0]; hvv[g * 4 + 1] = tv[1];
                    hvv[g * 4 + 2] = tv[2]; hvv[g * 4 + 3] = tv[3];
                }
                float e0 = db0, e1 = db1, e2 = db2;
#pragma unroll
                for (int o = 0; o < 16; ++o) {
                    e0 += hvv[o] * dw0[o]; e1 += hvv[o] * dw1[o]; e2 += hvv[o] * dw2[o];
                }
                unsigned short u0 = f2bf(e0), u1 = f2bf(e1), u2 = f2bf(e2);
                float f0 = bf2f(u0), f1 = bf2f(u1), f2v = bf2f(u2);
                sE2a += f0 * f0 + f1 * f1 + f2v * f2v;
                emL[lane * 160 + hw * 3 + 0] = u0;
                emL[lane * 160 + hw * 3 + 1] = u1;
                emL[lane * 160 + hw * 3 + 2] = u2;
            }
        }
    }
    sE2p[wv * 64 + lane] = sE2a;
    for (int e = tid; e < 64 * 13; e += 256) emL[(e / 13) * 160 + 147 + (e % 13)] = 0;
    __syncthreads();
    if (tid < 64) sE2f[tid] = sE2p[tid] + sE2p[64 + tid] + sE2p[128 + tid] + sE2p[192 + tid];
    __syncthreads();

    f32x4 aO[4];
#pragma unroll
    for (int j = 0; j < 4; ++j) aO[j] = (f32x4){0.f, 0.f, 0.f, 0.f};
    const unsigned short* xrow = Xg + (wv * 16 + l15) * 160 + q * 8;
#pragma unroll
    for (int s = 0; s < 5; ++s) {
        short8 af = *(const short8*)(xrow + s * 32);
#pragma unroll
        for (int j = 0; j < 4; ++j) {
            short8 bfv = *(const short8*)(emL + (j * 16 + l15) * 160 + s * 32 + q * 8);
            aO[j] = __builtin_amdgcn_mfma_f32_16x16x32_bf16(af, bfv, aO[j], 0, 0, 0);
        }
    }
    int b0 = wv * 16 + q * 4;
    float sxv[4];
#pragma unroll
    for (int r = 0; r < 4; ++r) sxv[r] = sx2g[b0 + r];
#pragma unroll
    for (int j = 0; j < 4; ++j) {
        int n = nbase + j * 16 + l15;
        float he = 0.5f * sE2f[j * 16 + l15];
#pragma unroll
        for (int r = 0; r < 4; ++r)
            out[(size_t)(b0 + r) * NNC + n] = aO[j][r] - he - 0.5f * sxv[r];
    }
}

// ============================ launcher ============================

extern "C" void kernel_launch(void* const* d_in, const int* in_sizes, int n_in,
                              void* d_out, int out_size, void* d_ws, size_t ws_size,
                              hipStream_t stream) {
    const float* x       = (const float*)d_in[0];
    const float* conv_w  = (const float*)d_in[1];
    const float* conv_b  = (const float*)d_in[2];
    const float* ebn2_g  = (const float*)d_in[3];
    const float* ebn2_b  = (const float*)d_in[4];
    const float* fc1_w   = (const float*)d_in[5];
    const float* fc1_b   = (const float*)d_in[6];
    const float* ebn1_g  = (const float*)d_in[7];
    const float* ebn1_b  = (const float*)d_in[8];
    const float* fc2_w   = (const float*)d_in[9];
    const float* fc2_b   = (const float*)d_in[10];
    const float* embeds  = (const float*)d_in[11];
    const float* dfc1_w  = (const float*)d_in[12];
    const float* dfc1_b  = (const float*)d_in[13];
    const float* dbn1_g  = (const float*)d_in[14];
    const float* dbn1_b  = (const float*)d_in[15];
    const float* dbn1_rm = (const float*)d_in[16];
    const float* dbn1_rv = (const float*)d_in[17];
    const float* dfc2_w  = (const float*)d_in[18];
    const float* dfc2_b  = (const float*)d_in[19];
    const float* dbn2_g  = (const float*)d_in[20];
    const float* dbn2_b  = (const float*)d_in[21];
    const float* dbn2_rm = (const float*)d_in[22];
    const float* dbn2_rv = (const float*)d_in[23];
    const float* dct1_w  = (const float*)d_in[24];
    const float* dct1_b  = (const float*)d_in[25];
    const float* dbn3_g  = (const float*)d_in[26];
    const float* dbn3_b  = (const float*)d_in[27];
    const float* dbn3_rm = (const float*)d_in[28];
    const float* dbn3_rv = (const float*)d_in[29];
    const float* dct2_w  = (const float*)d_in[30];
    const float* dct2_b  = (const float*)d_in[31];

    float* ws  = (float*)d_ws;
    float* out = (float*)d_out;

    dvae_k1<<<401, 256, 0, stream>>>(x, conv_w, conv_b, ebn2_g, ebn2_b,
                                     embeds, dfc1_w, dfc1_b, dbn1_g, dbn1_b, dbn1_rm, dbn1_rv,
                                     dfc2_w, dfc2_b, dbn2_g, dbn2_b, dbn2_rm, dbn2_rv,
                                     dct1_w, dct1_b, dbn3_g, dbn3_b, dbn3_rm, dbn3_rv, ws);

    hipFuncSetAttribute(reinterpret_cast<const void*>(dvae_k3),
                        hipFuncAttributeMaxDynamicSharedMemorySize, LDS_BYTES);
    dvae_k3<<<986, 256, LDS_BYTES, stream>>>(
        (const unsigned short*)(ws + WS_SH), (const unsigned short*)(ws + WS_S3),
        (const unsigned short*)(ws + WS_W2BF), ws + WS_C2,
        (const unsigned short*)(ws + WS_W3BF), ws + WS_C3,
        dct2_w, dct2_b,
        (const unsigned short*)(ws + WS_XBF), ws + WS_SX2,
        fc1_w, fc1_b, ebn1_g, ebn1_b,
        ws + WS_E1T, ws + WS_E2T, (int*)(ws + WS_FLAG),
        fc2_w, fc2_b, out);
}